// Round 2
// baseline (11002.828 us; speedup 1.0000x reference)
//
#include <hip/hip_runtime.h>
#include <cstdint>
#include <cstddef>

typedef short s16x8 __attribute__((ext_vector_type(8)));
typedef short s16x4 __attribute__((ext_vector_type(4)));
typedef float f32x4 __attribute__((ext_vector_type(4)));
typedef unsigned short u16;

#define DEVI __device__ __forceinline__

static constexpr int S_   = 2048;
static constexpr int D_   = 1024;
static constexpr int DIN_ = 2048;

DEVI float bf2f(u16 h){ return __uint_as_float(((uint32_t)h) << 16); }
DEVI u16 f2bf(float f){
  uint32_t u = __float_as_uint(f);
  u += 0x7fffu + ((u >> 16) & 1u);
  return (u16)(u >> 16);
}
DEVI float siluf(float x){ return x / (1.f + expf(-x)); }
DEVI float geluf(float x){
  return 0.5f * x * (1.f + tanhf(0.7978845608028654f * (x + 0.044715f * x * x * x)));
}

struct Epi {
  int mode, gcol, seq, tflags;
  float* of; u16* oh;
  const float* res; const float* beta; const float* bias; const float* gate;
  u16 *d0h, *d0l, *d1h, *d1l, *d2h, *d2l;
};

// C[M,N] = A[M,K] * B^T (B stored as [N,K]); bf16 hi(+lo), f32 accum.
// NP==4: (Ah+Al)(Bh+Bl) full 4 products. NP==1: hi only.
template<int NP>
__global__ __launch_bounds__(256)
void gemm_k(const u16* __restrict__ Ah, const u16* __restrict__ Al,
            const u16* __restrict__ Bh, const u16* __restrict__ Bl,
            int M, int N, int K, Epi e)
{
  __shared__ __align__(16) u16 sAh[128*32];
  __shared__ __align__(16) u16 sBh[128*32];
  __shared__ __align__(16) u16 sAl[NP==4 ? 128*32 : 8];
  __shared__ __align__(16) u16 sBl[NP==4 ? 128*32 : 8];

  const int t    = threadIdx.x;
  const int l15  = t & 15;
  const int quad = (t >> 4) & 3;
  const int w    = t >> 6;
  const int wm   = w >> 1, wn = w & 1;
  const size_t tm = (size_t)blockIdx.y * 128;
  const size_t tn = (size_t)blockIdx.x * 128;

  f32x4 zero4 = {0.f, 0.f, 0.f, 0.f};
  f32x4 acc[4][4];
#pragma unroll
  for (int i = 0; i < 4; i++)
#pragma unroll
    for (int j = 0; j < 4; j++) acc[i][j] = zero4;

  for (int k0 = 0; k0 < K; k0 += 32) {
    __syncthreads();
#pragma unroll
    for (int i = 0; i < 2; i++) {
      int idx = i * 256 + t;
      int q8  = idx >> 7;
      int m   = idx & 127;
      size_t ga = (tm + m) * (size_t)K + (size_t)k0 + q8 * 8;
      size_t gb = (tn + m) * (size_t)K + (size_t)k0 + q8 * 8;
      *(uint4*)&sAh[idx * 8] = *(const uint4*)&Ah[ga];
      *(uint4*)&sBh[idx * 8] = *(const uint4*)&Bh[gb];
      if (NP == 4) {
        *(uint4*)&sAl[idx * 8] = *(const uint4*)&Al[ga];
        *(uint4*)&sBl[idx * 8] = *(const uint4*)&Bl[gb];
      }
    }
    __syncthreads();

    s16x8 fah[4], fbh[4], fal[4], fbl[4];
#pragma unroll
    for (int i = 0; i < 4; i++) {
      fah[i] = *(const s16x8*)&sAh[(quad * 128 + wm * 64 + i * 16 + l15) * 8];
      fbh[i] = *(const s16x8*)&sBh[(quad * 128 + wn * 64 + i * 16 + l15) * 8];
      if (NP == 4) {
        fal[i] = *(const s16x8*)&sAl[(quad * 128 + wm * 64 + i * 16 + l15) * 8];
        fbl[i] = *(const s16x8*)&sBl[(quad * 128 + wn * 64 + i * 16 + l15) * 8];
      }
    }
#pragma unroll
    for (int mi = 0; mi < 4; mi++)
#pragma unroll
      for (int ni = 0; ni < 4; ni++) {
        acc[mi][ni] = __builtin_amdgcn_mfma_f32_16x16x32_bf16(fah[mi], fbh[ni], acc[mi][ni], 0, 0, 0);
        if (NP == 4) {
          acc[mi][ni] = __builtin_amdgcn_mfma_f32_16x16x32_bf16(fah[mi], fbl[ni], acc[mi][ni], 0, 0, 0);
          acc[mi][ni] = __builtin_amdgcn_mfma_f32_16x16x32_bf16(fal[mi], fbh[ni], acc[mi][ni], 0, 0, 0);
          acc[mi][ni] = __builtin_amdgcn_mfma_f32_16x16x32_bf16(fal[mi], fbl[ni], acc[mi][ni], 0, 0, 0);
        }
      }
  }

#pragma unroll
  for (int mi = 0; mi < 4; mi++)
#pragma unroll
    for (int ni = 0; ni < 4; ni++)
#pragma unroll
      for (int r = 0; r < 4; r++) {
        size_t row = tm + wm * 64 + mi * 16 + quad * 4 + r;
        size_t col = tn + wn * 64 + ni * 16 + l15;
        float v = acc[mi][ni][r];
        size_t idx = row * (size_t)N + col;
        switch (e.mode) {
          case 0: e.of[idx] = siluf(v); break;
          case 1: e.of[idx] = e.res[idx] + e.beta[col] * v; break;
          case 2: e.of[idx] += e.beta[col] * v; break;
          case 3: {
            int part = (int)(col >> 10);
            int rr   = (int)(col & 1023);
            int hh8  = rr >> 6, hd = rr & 63;
            int bb   = (int)(row / (size_t)e.seq);
            int ssx  = (int)(row - (size_t)bb * e.seq);
            u16* dh = (part == 0) ? e.d0h : ((part == 1) ? e.d1h : e.d2h);
            u16* dl = (part == 0) ? e.d0l : ((part == 1) ? e.d1l : e.d2l);
            size_t o;
            if ((e.tflags >> part) & 1)
              o = ((size_t)(bb * 16 + hh8) * 64 + hd) * (size_t)e.seq + ssx;
            else
              o = ((size_t)(bb * 16 + hh8) * (size_t)e.seq + ssx) * 64 + hd;
            u16 vh = f2bf(v);
            dh[o] = vh;
            if (dl) dl[o] = f2bf(v - bf2f(vh));
          } break;
          case 4: {
            float xx = v + (e.bias ? e.bias[col] : 0.f);
            e.oh[idx] = f2bf(geluf(xx));
          } break;
          case 5: e.of[idx] = e.res[idx] + v + e.bias[col]; break;
          case 6: e.of[idx] += e.gate[row * 8 + e.gcol] * v; break;
          case 7: e.oh[idx] = f2bf(e.res[idx] + v); break;
        }
      }
}

// Flash attention. Inputs pre-split bf16: Qh/Ql [BH,Sq,64], Kh/Kl [BH,Skv,64],
// Vth/Vtl [BH,64,Skv]. Out bf16 hi(+lo) at [(b*Sq+s)*1024 + h*64 + hd].
template<int NP, int CAUSAL>
__global__ __launch_bounds__(256)
void flash_k(const u16* __restrict__ Qh, const u16* __restrict__ Ql,
             const u16* __restrict__ Kh, const u16* __restrict__ Kl,
             const u16* __restrict__ Vth, const u16* __restrict__ Vtl,
             u16* __restrict__ Ohi, u16* __restrict__ Olo, int Sq, int Skv, float scale)
{
  constexpr int LDP = 72;
  __shared__ __align__(16) u16 sQh[64 * LDP];
  __shared__ __align__(16) u16 sKh[64 * LDP];
  __shared__ __align__(16) u16 sVh[64 * LDP];
  __shared__ __align__(16) u16 sPh[64 * LDP];
  __shared__ __align__(16) u16 sQl[NP==3 ? 64*LDP : 8];
  __shared__ __align__(16) u16 sKl[NP==3 ? 64*LDP : 8];
  __shared__ __align__(16) u16 sVl[NP==3 ? 64*LDP : 8];
  __shared__ __align__(16) u16 sPl[NP==3 ? 64*LDP : 8];

  const int qt = blockIdx.x, bh = blockIdx.y;
  const int b = bh >> 4, h = bh & 15;
  const int t = threadIdx.x;
  const int w = t >> 6, l15 = t & 15, quad = (t >> 4) & 3;

  {
    size_t qbase = ((size_t)bh * Sq + (size_t)qt * 64) * 64;
#pragma unroll
    for (int i = 0; i < 2; i++) {
      int idx = i * 256 + t;
      int r = idx >> 3, c = (idx & 7) * 8;
      *(uint4*)&sQh[r * LDP + c] = *(const uint4*)&Qh[qbase + (size_t)r * 64 + c];
      if (NP == 3)
        *(uint4*)&sQl[r * LDP + c] = *(const uint4*)&Ql[qbase + (size_t)r * 64 + c];
    }
  }

  float m_r[4] = {-1e30f, -1e30f, -1e30f, -1e30f};
  float l_r[4] = {0.f, 0.f, 0.f, 0.f};
  f32x4 zero4 = {0.f, 0.f, 0.f, 0.f};
  f32x4 O[4];
#pragma unroll
  for (int i = 0; i < 4; i++) O[i] = zero4;

  const int nkt = CAUSAL ? (qt + 1) : (Skv >> 6);
  for (int kt = 0; kt < nkt; kt++) {
    __syncthreads();
    {
      size_t kbase = ((size_t)bh * Skv + (size_t)kt * 64) * 64;
      size_t vbase = (size_t)bh * 64 * (size_t)Skv + (size_t)kt * 64;
#pragma unroll
      for (int i = 0; i < 2; i++) {
        int idx = i * 256 + t;
        int r = idx >> 3, c = (idx & 7) * 8;
        *(uint4*)&sKh[r * LDP + c] = *(const uint4*)&Kh[kbase + (size_t)r * 64 + c];
        *(uint4*)&sVh[r * LDP + c] = *(const uint4*)&Vth[vbase + (size_t)r * Skv + c];
        if (NP == 3) {
          *(uint4*)&sKl[r * LDP + c] = *(const uint4*)&Kl[kbase + (size_t)r * 64 + c];
          *(uint4*)&sVl[r * LDP + c] = *(const uint4*)&Vtl[vbase + (size_t)r * Skv + c];
        }
      }
    }
    __syncthreads();

    float sv[4][4];
#pragma unroll
    for (int ni = 0; ni < 4; ni++) {
      f32x4 a = zero4;
#pragma unroll
      for (int ks2 = 0; ks2 < 2; ks2++) {
        s16x8 qa = *(const s16x8*)&sQh[(w * 16 + l15) * LDP + ks2 * 32 + quad * 8];
        s16x8 kb = *(const s16x8*)&sKh[(ni * 16 + l15) * LDP + ks2 * 32 + quad * 8];
        a = __builtin_amdgcn_mfma_f32_16x16x32_bf16(qa, kb, a, 0, 0, 0);
        if (NP == 3) {
          s16x8 ql = *(const s16x8*)&sQl[(w * 16 + l15) * LDP + ks2 * 32 + quad * 8];
          s16x8 kl = *(const s16x8*)&sKl[(ni * 16 + l15) * LDP + ks2 * 32 + quad * 8];
          a = __builtin_amdgcn_mfma_f32_16x16x32_bf16(qa, kl, a, 0, 0, 0);
          a = __builtin_amdgcn_mfma_f32_16x16x32_bf16(ql, kb, a, 0, 0, 0);
        }
      }
      sv[ni][0] = a[0]; sv[ni][1] = a[1]; sv[ni][2] = a[2]; sv[ni][3] = a[3];
    }

    float mt[4] = {-1e30f, -1e30f, -1e30f, -1e30f};
#pragma unroll
    for (int ni = 0; ni < 4; ni++)
#pragma unroll
      for (int r = 0; r < 4; r++) {
        float v = sv[ni][r] * scale;
        if (CAUSAL) {
          int qi = qt * 64 + w * 16 + quad * 4 + r;
          int ki = kt * 64 + ni * 16 + l15;
          if (ki > qi) v = -1e30f;
        }
        sv[ni][r] = v;
        mt[r] = fmaxf(mt[r], v);
      }
#pragma unroll
    for (int off = 1; off < 16; off <<= 1)
#pragma unroll
      for (int r = 0; r < 4; r++) mt[r] = fmaxf(mt[r], __shfl_xor(mt[r], off));

    float alpha[4];
#pragma unroll
    for (int r = 0; r < 4; r++) {
      float mn = fmaxf(m_r[r], mt[r]);
      alpha[r] = expf(m_r[r] - mn);
      m_r[r] = mn;
    }
    float rsum[4] = {0.f, 0.f, 0.f, 0.f};
#pragma unroll
    for (int ni = 0; ni < 4; ni++)
#pragma unroll
      for (int r = 0; r < 4; r++) {
        float pv = expf(sv[ni][r] - m_r[r]);
        sv[ni][r] = pv;
        rsum[r] += pv;
      }
#pragma unroll
    for (int off = 1; off < 16; off <<= 1)
#pragma unroll
      for (int r = 0; r < 4; r++) rsum[r] += __shfl_xor(rsum[r], off);
#pragma unroll
    for (int r = 0; r < 4; r++) l_r[r] = l_r[r] * alpha[r] + rsum[r];
#pragma unroll
    for (int ni = 0; ni < 4; ni++)
#pragma unroll
      for (int r = 0; r < 4; r++) O[ni][r] *= alpha[r];

    // P: C-layout -> wave-private LDS -> A-layout
#pragma unroll
    for (int ni = 0; ni < 4; ni++)
#pragma unroll
      for (int r = 0; r < 4; r++) {
        float pv = sv[ni][r];
        u16 ph = f2bf(pv);
        sPh[(w * 16 + quad * 4 + r) * LDP + ni * 16 + l15] = ph;
        if (NP == 3)
          sPl[(w * 16 + quad * 4 + r) * LDP + ni * 16 + l15] = f2bf(pv - bf2f(ph));
      }
    asm volatile("s_waitcnt lgkmcnt(0)" ::: "memory");

#pragma unroll
    for (int ni = 0; ni < 4; ni++) {
#pragma unroll
      for (int ks2 = 0; ks2 < 2; ks2++) {
        s16x8 pa = *(const s16x8*)&sPh[(w * 16 + l15) * LDP + ks2 * 32 + quad * 8];
        s16x8 vb = *(const s16x8*)&sVh[(ni * 16 + l15) * LDP + ks2 * 32 + quad * 8];
        O[ni] = __builtin_amdgcn_mfma_f32_16x16x32_bf16(pa, vb, O[ni], 0, 0, 0);
        if (NP == 3) {
          s16x8 pl = *(const s16x8*)&sPl[(w * 16 + l15) * LDP + ks2 * 32 + quad * 8];
          s16x8 vl = *(const s16x8*)&sVl[(ni * 16 + l15) * LDP + ks2 * 32 + quad * 8];
          O[ni] = __builtin_amdgcn_mfma_f32_16x16x32_bf16(pa, vl, O[ni], 0, 0, 0);
          O[ni] = __builtin_amdgcn_mfma_f32_16x16x32_bf16(pl, vb, O[ni], 0, 0, 0);
        }
      }
    }
  }

#pragma unroll
  for (int ni = 0; ni < 4; ni++)
#pragma unroll
    for (int r = 0; r < 4; r++) {
      int qi = qt * 64 + w * 16 + quad * 4 + r;
      float o = O[ni][r] / l_r[r];
      size_t addr = ((size_t)b * Sq + qi) * 1024 + h * 64 + ni * 16 + l15;
      u16 oh = f2bf(o);
      Ohi[addr] = oh;
      if (NP == 3) Olo[addr] = f2bf(o - bf2f(oh));
    }
}

// transpose + f32->bf16 hi(+lo): W [K,N] -> T [N,K]; grid (K/32, N/32)
__global__ __launch_bounds__(256)
void cvtT_k(const float* __restrict__ W, u16* __restrict__ Th, u16* __restrict__ Tl,
            int K, int N)
{
  __shared__ float tile[32][33];
  int k0 = blockIdx.x * 32, n0 = blockIdx.y * 32;
  int t = threadIdx.x;
  int r = t >> 5, c = t & 31;
#pragma unroll
  for (int i = 0; i < 4; i++)
    tile[r + i * 8][c] = W[(size_t)(k0 + r + i * 8) * N + n0 + c];
  __syncthreads();
#pragma unroll
  for (int i = 0; i < 4; i++) {
    int n = r + i * 8;
    int k = c;
    float v = tile[k][n];
    u16 hh = f2bf(v);
    Th[(size_t)(n0 + n) * K + k0 + k] = hh;
    if (Tl) Tl[(size_t)(n0 + n) * K + k0 + k] = f2bf(v - bf2f(hh));
  }
}

__global__ __launch_bounds__(256)
void cvt_h_k(const float* __restrict__ in, u16* __restrict__ o, size_t n)
{
  size_t base = ((size_t)blockIdx.x * 256 + threadIdx.x) * 4;
  if (base < n) {
    float4 v = *(const float4*)&in[base];
    s16x4 hv = {(short)f2bf(v.x), (short)f2bf(v.y), (short)f2bf(v.z), (short)f2bf(v.w)};
    *(s16x4*)&o[base] = hv;
  }
}

__global__ __launch_bounds__(256)
void ln_k(const float* __restrict__ x, const float* __restrict__ gamma,
          const float* __restrict__ beta, u16* __restrict__ hh, u16* __restrict__ hl)
{
  int row = blockIdx.x;
  int t = threadIdx.x;
  const float4* xr = (const float4*)(x + (size_t)row * D_);
  float4 v = xr[t];
  float s = v.x + v.y + v.z + v.w;
  float q = v.x * v.x + v.y * v.y + v.z * v.z + v.w * v.w;
#pragma unroll
  for (int off = 1; off < 64; off <<= 1) { s += __shfl_xor(s, off); q += __shfl_xor(q, off); }
  __shared__ float ss[4], sq2[4];
  if ((t & 63) == 0) { ss[t >> 6] = s; sq2[t >> 6] = q; }
  __syncthreads();
  s = ss[0] + ss[1] + ss[2] + ss[3];
  q = sq2[0] + sq2[1] + sq2[2] + sq2[3];
  float mean = s * (1.f / D_);
  float var = q * (1.f / D_) - mean * mean;
  float rstd = 1.f / sqrtf(var + 1e-5f);
  float4 gv = ((const float4*)gamma)[t];
  float4 bv = ((const float4*)beta)[t];
  float o0 = (v.x - mean) * rstd * gv.x + bv.x;
  float o1 = (v.y - mean) * rstd * gv.y + bv.y;
  float o2 = (v.z - mean) * rstd * gv.z + bv.z;
  float o3 = (v.w - mean) * rstd * gv.w + bv.w;
  u16 h0 = f2bf(o0), h1 = f2bf(o1), h2 = f2bf(o2), h3 = f2bf(o3);
  s16x4 hv = {(short)h0, (short)h1, (short)h2, (short)h3};
  *(s16x4*)&hh[(size_t)row * D_ + t * 4] = hv;
  s16x4 lv = {(short)f2bf(o0 - bf2f(h0)), (short)f2bf(o1 - bf2f(h1)),
              (short)f2bf(o2 - bf2f(h2)), (short)f2bf(o3 - bf2f(h3))};
  *(s16x4*)&hl[(size_t)row * D_ + t * 4] = lv;
}

// SSM scan, chunked (1024 rows per chunk = 8 chains of 128). u local [1024, DIN].
__global__ __launch_bounds__(256)
void scan_part_k(const float* __restrict__ u, const float* __restrict__ Alog,
                 float* __restrict__ Lb, int lbBase)
{
  int d = blockIdx.x * 256 + threadIdx.x;
  int chl = blockIdx.y;
  float a = 1.f / (1.f + expf(-Alog[d]));
  float c = 0.f;
  const float* up = u + (size_t)(chl * 128) * DIN_ + d;
  for (int i = 0; i < 128; i++) c = a * c + (1.f - a) * up[(size_t)i * DIN_];
  Lb[(size_t)(lbBase + chl) * DIN_ + d] = c;
}

__global__ __launch_bounds__(256)
void scan_carry_k(const float* __restrict__ Lb, const float* __restrict__ Alog,
                  float* __restrict__ Cb)
{
  int d = blockIdx.x * 256 + threadIdx.x;
  int b = blockIdx.y;
  float a = 1.f / (1.f + expf(-Alog[d]));
  float pw = a;
#pragma unroll
  for (int i = 0; i < 7; i++) pw *= pw;   // a^128
  float carry = 0.f;
  for (int ch = 0; ch < 16; ch++) {
    Cb[(size_t)(b * 16 + ch) * DIN_ + d] = carry;
    carry = pw * carry + Lb[(size_t)(b * 16 + ch) * DIN_ + d];
  }
}

__global__ __launch_bounds__(256)
void scan_final_k(const float* __restrict__ u, const float* __restrict__ g,
                  const float* __restrict__ Alog, const float* __restrict__ Cb,
                  u16* __restrict__ ysh, u16* __restrict__ ysl, int cbBase, int gRow0)
{
  int d = blockIdx.x * 256 + threadIdx.x;
  int chl = blockIdx.y;
  float a = 1.f / (1.f + expf(-Alog[d]));
  float c = Cb[(size_t)(cbBase + chl) * DIN_ + d];
  size_t lbase = (size_t)(chl * 128) * DIN_ + d;
  size_t gbase = (size_t)(gRow0 + chl * 128) * DIN_ + d;
  for (int i = 0; i < 128; i++) {
    size_t li = lbase + (size_t)i * DIN_;
    size_t gi = gbase + (size_t)i * DIN_;
    c = a * c + (1.f - a) * u[li];
    float y = c * g[li];
    u16 hh = f2bf(y);
    ysh[gi] = hh;
    ysl[gi] = f2bf(y - bf2f(hh));
  }
}

__global__ __launch_bounds__(256)
void router_k(const float* __restrict__ xm, const float* __restrict__ rW,
              const float* __restrict__ rb, const float* __restrict__ encA,
              float* __restrict__ gate)
{
  int row = blockIdx.x;
  int t = threadIdx.x;
  const float4* xr = (const float4*)(xm + (size_t)row * D_);
  float4 v = xr[t];
  float acc[8] = {0.f, 0.f, 0.f, 0.f, 0.f, 0.f, 0.f, 0.f};
#pragma unroll
  for (int c = 0; c < 4; c++) {
    int d = t * 4 + c;
    const float* wr = rW + (size_t)d * 8;
    float xv = (&v.x)[c];
#pragma unroll
    for (int e8 = 0; e8 < 8; e8++) acc[e8] += xv * wr[e8];
  }
#pragma unroll
  for (int off = 1; off < 64; off <<= 1)
#pragma unroll
    for (int e8 = 0; e8 < 8; e8++) acc[e8] += __shfl_xor(acc[e8], off);
  __shared__ float red[4][8];
  if ((t & 63) == 0)
#pragma unroll
    for (int e8 = 0; e8 < 8; e8++) red[t >> 6][e8] = acc[e8];
  __syncthreads();
  if (t == 0) {
    int b = row >> 11;
    float ea = encA[b];
    float lg[8];
#pragma unroll
    for (int e8 = 0; e8 < 8; e8++)
      lg[e8] = red[0][e8] + red[1][e8] + red[2][e8] + red[3][e8] + ea * rW[1024 * 8 + e8] + rb[e8];
    int i1 = 0;
#pragma unroll
    for (int e8 = 1; e8 < 8; e8++) if (lg[e8] > lg[i1]) i1 = e8;
    int i2 = -1;
#pragma unroll
    for (int e8 = 0; e8 < 8; e8++)
      if (e8 != i1 && (i2 < 0 || lg[e8] > lg[i2])) i2 = e8;
    float e2 = expf(lg[i2] - lg[i1]);
    float w1 = 1.f / (1.f + e2);
    float w2 = e2 / (1.f + e2);
    float* gr = gate + (size_t)row * 8;
#pragma unroll
    for (int e8 = 0; e8 < 8; e8++) gr[e8] = 0.f;
    gr[i1] = w1;
    gr[i2] = w2;
  }
}

__global__ __launch_bounds__(256)
void diag_k(float* __restrict__ out, size_t n, float val)
{
  size_t i = (size_t)blockIdx.x * 256 + threadIdx.x;
  if (i < n) out[i] = (i == 0) ? val : 0.f;
}

extern "C" void kernel_launch(void* const* d_in, const int* in_sizes, int n_in,
                              void* d_out, int out_size, void* d_ws, size_t ws_size,
                              hipStream_t stream)
{
  (void)in_sizes; (void)n_in;
  const float* x     = (const float*)d_in[0];
  const float* enc   = (const float*)d_in[1];
  const float* encA  = (const float*)d_in[2];
  const float* lng   = (const float*)d_in[3];
  const float* lnb   = (const float*)d_in[4];
  const float* Win   = (const float*)d_in[5];
  const float* Wgate = (const float*)d_in[6];
  const float* Alog  = (const float*)d_in[7];
  const float* Wout  = (const float*)d_in[8];
  const float* Wqkv  = (const float*)d_in[9];
  const float* Wo    = (const float*)d_in[10];
  const float* bSsm  = (const float*)d_in[11];
  const float* bAttn = (const float*)d_in[12];
  const float* shW1  = (const float*)d_in[13];
  const float* shb1  = (const float*)d_in[14];
  const float* shW2  = (const float*)d_in[15];
  const float* shb2  = (const float*)d_in[16];
  const float* rW    = (const float*)d_in[17];
  const float* rb    = (const float*)d_in[18];
  const float* AWq   = (const float*)d_in[19];
  const float* AWk   = (const float*)d_in[20];
  const float* AWv   = (const float*)d_in[21];
  const float* AWo   = (const float*)d_in[22];
  const float* AW1   = (const float*)d_in[23];
  const float* AW2   = (const float*)d_in[24];
  const float* BW1   = (const float*)d_in[25];
  const float* BW2   = (const float*)d_in[26];
  float* out = (float*)d_out;

  const size_t MB = 1024 * 1024;
  const size_t NEED = 157 * MB;
  if (ws_size < NEED) {   // diagnostic: absmax ~= ws_size
    diag_k<<<dim3((out_size + 255) / 256), 256, 0, stream>>>(out, (size_t)out_size, (float)ws_size);
    return;
  }

  char* ws = (char*)d_ws;
  // arena layout (bytes)
  char* W    = ws;                 // 24 MB rotating weight arena
  char* PA   = ws + 24 * MB;       // 48 MB: SSM u/g chunks -> qkv split bf16
  char* PB   = ws + 72 * MB;       // 32 MB: ysh/ysl -> ff1
  char* PC   = ws + 104 * MB;      // 16 MB: hh/hl -> ath/atl
  float* xm  = (float*)(ws + 120 * MB);   // 16 MB
  u16* xfb   = (u16*)(ws + 136 * MB);     // 8 MB
  u16* heb   = (u16*)(ws + 144 * MB);     // 8 MB
  u16* ench  = (u16*)(ws + 152 * MB);     // 4 MB
  float* Lb  = (float*)(ws + 156 * MB);          // 256 KB
  float* Cb  = (float*)(ws + 156 * MB + 262144); // 256 KB
  float* gate= (float*)(ws + 156 * MB + 524288); // 128 KB

  float* u_ch = (float*)(PA);
  float* g_ch = (float*)(PA + 8 * MB);
  u16* qh  = (u16*)(PA);            u16* ql  = (u16*)(PA + 8 * MB);
  u16* kh  = (u16*)(PA + 16 * MB);  u16* kl  = (u16*)(PA + 24 * MB);
  u16* vth = (u16*)(PA + 32 * MB);  u16* vtl = (u16*)(PA + 40 * MB);
  u16* ysh = (u16*)(PB);            u16* ysl = (u16*)(PB + 16 * MB);
  u16* ff1 = (u16*)(PB);
  u16* hh  = (u16*)(PC);            u16* hl  = (u16*)(PC + 8 * MB);
  u16* ath = (u16*)(PC);            u16* atl = (u16*)(PC + 8 * MB);

  auto E0 = [](int mode) {
    Epi e; e.mode = mode; e.gcol = 0; e.seq = 1; e.tflags = 0;
    e.of = nullptr; e.oh = nullptr;
    e.res = nullptr; e.beta = nullptr; e.bias = nullptr; e.gate = nullptr;
    e.d0h = e.d0l = e.d1h = e.d1l = e.d2h = e.d2l = nullptr;
    return e;
  };
  auto g4 = [&](const u16* Ah, const u16* Al, const u16* Bh, const u16* Bl,
                int M, int N, int K, Epi e) {
    gemm_k<4><<<dim3(N / 128, M / 128), 256, 0, stream>>>(Ah, Al, Bh, Bl, M, N, K, e);
  };
  auto g1 = [&](const u16* Ah, const u16* Bh, int M, int N, int K, Epi e) {
    gemm_k<1><<<dim3(N / 128, M / 128), 256, 0, stream>>>(Ah, nullptr, Bh, nullptr, M, N, K, e);
  };
  auto ct = [&](const float* Wsrc, u16* Th, u16* Tl, int K, int N) {
    cvtT_k<<<dim3(K / 32, N / 32), 256, 0, stream>>>(Wsrc, Th, Tl, K, N);
  };

  // weight arena slot pointers (per phase; stream order serializes reuse)
  u16* W0h = (u16*)(W);
  u16* W0l = (u16*)(W + 4 * MB);
  u16* W1h = (u16*)(W + 8 * MB);
  u16* W1l = (u16*)(W + 12 * MB);

  // ---- pre-router path (split bf16, 4-product) ----
  ln_k<<<dim3(4096), 256, 0, stream>>>(x, lng, lnb, hh, hl);

  // SSM: chunked (4 x 1024 rows)
  ct(Win,   W0h, W0l, 1024, 2048);       // Win^T  hi/lo @ W+0/W+4MB
  ct(Wgate, W1h, W1l, 1024, 2048);       // Wg^T   hi/lo @ W+8MB/W+12MB
  for (int c = 0; c < 4; c++) {
    Epi e = E0(0); e.of = u_ch;
    g4(hh + (size_t)c * 1024 * 1024, hl + (size_t)c * 1024 * 1024, W0h, W0l,
       1024, 2048, 1024, e);
    scan_part_k<<<dim3(DIN_ / 256, 8), 256, 0, stream>>>(u_ch, Alog, Lb, c * 8);
  }
  scan_carry_k<<<dim3(DIN_ / 256, 2), 256, 0, stream>>>(Lb, Alog, Cb);
  for (int c = 0; c < 4; c++) {
    { Epi e = E0(0); e.of = u_ch;
      g4(hh + (size_t)c * 1024 * 1024, hl + (size_t)c * 1024 * 1024, W0h, W0l,
         1024, 2048, 1024, e); }
    { Epi e = E0(0); e.of = g_ch;
      g4(hh + (size_t)c * 1024 * 1024, hl + (size_t)c * 1024 * 1024, W1h, W1l,
         1024, 2048, 1024, e); }
    scan_final_k<<<dim3(DIN_ / 256, 8), 256, 0, stream>>>(u_ch, g_ch, Alog, Cb,
                                                          ysh, ysl, c * 8, c * 1024);
  }
  // ssm_out @ Wout -> xm = x + beta_ssm * v
  ct(Wout, W0h, W0l, 2048, 1024);
  { Epi e = E0(1); e.of = xm; e.res = x; e.beta = bSsm;
    g4(ysh, ysl, W0h, W0l, 4096, 1024, 2048, e); }

  // QKV -> split bf16 q/k/vt
  { u16* Qh_ = (u16*)(W); u16* Ql_ = (u16*)(W + 8 * MB);
    ct(Wqkv, Qh_, Ql_, 1024, 3072);
    Epi e = E0(3); e.seq = 2048; e.tflags = 4;
    e.d0h = qh; e.d0l = ql; e.d1h = kh; e.d1l = kl; e.d2h = vth; e.d2l = vtl;
    g4(hh, hl, Qh_, Ql_, 4096, 3072, 1024, e); }
  flash_k<3, 1><<<dim3(32, 32), 256, 0, stream>>>(qh, ql, kh, kl, vth, vtl,
                                                  ath, atl, 2048, 2048, 0.125f);
  ct(Wo, W0h, W0l, 1024, 1024);
  { Epi e = E0(2); e.of = xm; e.beta = bAttn;
    g4(ath, atl, W0h, W0l, 4096, 1024, 1024, e); }

  // ---- router ----
  cvt_h_k<<<dim3(4 * MB / 1024), 256, 0, stream>>>(xm, xfb, 4 * MB);
  router_k<<<dim3(4096), 256, 0, stream>>>(xm, rW, rb, encA, gate);
  cvt_h_k<<<dim3(2 * MB / 1024), 256, 0, stream>>>(enc, ench, 2 * MB);

  // ---- shared FFN -> out = xm + shared ----
  { u16* S1 = (u16*)(W); u16* S2 = (u16*)(W + 8 * MB);
    ct(shW1, S1, nullptr, 1024, 4096);
    { Epi e = E0(4); e.oh = ff1; e.bias = shb1; g1(xfb, S1, 4096, 4096, 1024, e); }
    ct(shW2, S2, nullptr, 4096, 1024);
    { Epi e = E0(5); e.of = out; e.res = xm; e.bias = shb2;
      g1(ff1, S2, 4096, 1024, 4096, e); } }

  // ---- A experts (cross-attn + FFN), dense, gated ----
  for (int ex = 0; ex < 2; ex++) {
    u16* Wq_ = (u16*)(W);            u16* Wk_ = (u16*)(W + 2 * MB);
    u16* Wv_ = (u16*)(W + 4 * MB);   u16* Wo_ = (u16*)(W + 6 * MB);
    u16* Wf1 = (u16*)(W + 8 * MB);   u16* Wf2 = (u16*)(W + 16 * MB);
    ct(AWq + (size_t)ex * MB, Wq_, nullptr, 1024, 1024);
    ct(AWk + (size_t)ex * MB, Wk_, nullptr, 1024, 1024);
    ct(AWv + (size_t)ex * MB, Wv_, nullptr, 1024, 1024);
    ct(AWo + (size_t)ex * MB, Wo_, nullptr, 1024, 1024);
    ct(AW1 + (size_t)ex * 4 * MB, Wf1, nullptr, 1024, 4096);
    ct(AW2 + (size_t)ex * 4 * MB, Wf2, nullptr, 4096, 1024);
    { Epi e = E0(3); e.seq = 2048; e.tflags = 0; e.d0h = qh;
      g1(xfb, Wq_, 4096, 1024, 1024, e); }
    { Epi e = E0(3); e.seq = 1024; e.tflags = 0; e.d0h = kh;
      g1(ench, Wk_, 2048, 1024, 1024, e); }
    { Epi e = E0(3); e.seq = 1024; e.tflags = 1; e.d0h = vth;
      g1(ench, Wv_, 2048, 1024, 1024, e); }
    flash_k<1, 0><<<dim3(32, 32), 256, 0, stream>>>(qh, nullptr, kh, nullptr, vth, nullptr,
                                                    ath, nullptr, 2048, 1024, 0.125f);
    { Epi e = E0(7); e.oh = heb; e.res = xm;
      g1(ath, Wo_, 4096, 1024, 1024, e); }
    { Epi e = E0(4); e.oh = ff1;
      g1(heb, Wf1, 4096, 4096, 1024, e); }
    { Epi e = E0(6); e.of = out; e.gate = gate; e.gcol = ex;
      g1(ff1, Wf2, 4096, 1024, 4096, e); }
  }

  // ---- B experts (FFN), dense, gated ----
  for (int j = 0; j < 6; j++) {
    u16* Wf1 = (u16*)(W);            u16* Wf2 = (u16*)(W + 8 * MB);
    ct(BW1 + (size_t)j * 4 * MB, Wf1, nullptr, 1024, 4096);
    ct(BW2 + (size_t)j * 4 * MB, Wf2, nullptr, 4096, 1024);
    { Epi e = E0(4); e.oh = ff1;
      g1(xfb, Wf1, 4096, 4096, 1024, e); }
    { Epi e = E0(6); e.of = out; e.gate = gate; e.gcol = 2 + j;
      g1(ff1, Wf2, 4096, 1024, 4096, e); }
  }
}